// Round 1
// baseline (788.181 us; speedup 1.0000x reference)
//
#include <hip/hip_runtime.h>

typedef _Float16 f16x8 __attribute__((ext_vector_type(8)));
typedef float    f32x4 __attribute__((ext_vector_type(4)));
typedef unsigned short ushort_t;

__device__ __forceinline__ ushort_t f2h(float x) {
    union { _Float16 h; ushort_t u; } c; c.h = (_Float16)x; return c.u;
}

// async global->LDS, 16 B per lane; LDS dest = wave-uniform base + lane*16
typedef __attribute__((address_space(1))) void gvoid;
typedef __attribute__((address_space(3))) void lvoid;
__device__ __forceinline__ void g2l16(const ushort_t* g, ushort_t* l) {
    __builtin_amdgcn_global_load_lds((gvoid*)g, (lvoid*)l, 16, 0, 0);
}

#define BM 128
#define BN 128
#define BK 32
#define NT 256

// ---------- weight transpose+convert: W[k][n] fp32 -> WT[n][k] fp16 ----------
__global__ void wconv_kernel(const float* __restrict__ Wq, const float* __restrict__ Wk,
                             const float* __restrict__ Wv,
                             ushort_t* __restrict__ tq, ushort_t* __restrict__ tk,
                             ushort_t* __restrict__ tv) {
    const int z = blockIdx.z;
    const float* W = (z == 0) ? Wq : (z == 1) ? Wk : Wv;
    ushort_t* T = (z == 0) ? tq : (z == 1) ? tk : tv;
    const int n  = blockIdx.x * blockDim.x + threadIdx.x;   // 0..1023
    const int kb = blockIdx.y * 128;                        // k range per block
    for (int k0 = kb; k0 < kb + 128; k0 += 8) {
        union { ushort_t u[8]; uint4 v; } H;
        #pragma unroll
        for (int e = 0; e < 8; ++e)
            H.u[e] = f2h(W[(long long)(k0 + e) * 1024 + n]);   // coalesced across lanes
        *(uint4*)&T[(long long)n * 1024 + k0] = H.v;           // per-lane contiguous 16B
    }
}

// ---------- activation convert: fp32 -> fp16 ----------
__global__ void aconv_kernel(const float* __restrict__ x, ushort_t* __restrict__ h, int n4) {
    int i = blockIdx.x * blockDim.x + threadIdx.x;
    if (i >= n4) return;
    float4 v = ((const float4*)x)[i];
    union { ushort_t u[4]; uint2 w; } H;
    H.u[0] = f2h(v.x); H.u[1] = f2h(v.y); H.u[2] = f2h(v.z); H.u[3] = f2h(v.w);
    ((uint2*)h)[i] = H.w;
}

// ---------- output zeroing (for split-K atomic accumulate) ----------
__global__ void zero_kernel(float4* __restrict__ p, int n4) {
    int i = blockIdx.x * blockDim.x + threadIdx.x;
    if (i < n4) p[i] = float4{0.f, 0.f, 0.f, 0.f};
}

// ---------- fp16 GEMM (m97 structure): C[M,N] = A[m][k] * B[n][k]^T (+bias) ----------
// OUT_MODE: 0 = fp32 [m][n]; 1 = fp16 [m][n]; 3 = fp16 transposed [n][m], batched along m by tM
//           4 = fp32 atomicAdd [m][n] (split-K partial accumulate; requires pre-zeroed C)
// NSPLIT: K-split factor; blockIdx.z = batch*NSPLIT + k_chunk, each chunk covers K elems
template<int OUT_MODE, bool BIAS, int NSPLIT>
__global__ __launch_bounds__(NT, 2)
void gemm_kernel(const ushort_t* __restrict__ A, const ushort_t* __restrict__ B,
                 const float* __restrict__ bias,
                 float* __restrict__ Cf, ushort_t* __restrict__ Ch,
                 int K, int lda, int ldb, int ldc,
                 long long sA, long long sB, long long sC, int tM)
{
    __shared__ __align__(16) ushort_t As[BM * BK];
    __shared__ __align__(16) ushort_t Bs[BN * BK];
    __shared__ float biasS[BN];

    const int tid  = threadIdx.x;
    const int zz   = blockIdx.z;
    const int b    = zz / NSPLIT;           // batch index
    const int kc   = zz % NSPLIT;           // K-chunk index
    const int m0   = blockIdx.y * BM;
    const int n0   = blockIdx.x * BN;
    const int lane = tid & 63;
    const int w    = tid >> 6;
    const int wm   = (w >> 1) * 64;
    const int wn   = (w & 1) * 64;
    const int l15  = lane & 15;
    const int quad = lane >> 4;

    if (BIAS && tid < BN) biasS[tid] = bias[n0 + tid];

    const long long aBase = (long long)b * sA + (long long)m0 * lda;
    const long long bBase = (long long)b * sB + (long long)n0 * ldb;

    f32x4 acc[4][4];
    #pragma unroll
    for (int i = 0; i < 4; ++i)
        #pragma unroll
        for (int j = 0; j < 4; ++j)
            #pragma unroll
            for (int r = 0; r < 4; ++r) acc[i][j][r] = 0.0f;

    const int kBeg = kc * K;
    const int kEnd = kBeg + K;
    for (int k0 = kBeg; k0 < kEnd; k0 += BK) {
        __syncthreads();   // previous tile's frag reads done before overwrite
        {
            const int row = tid >> 2;            // 64 rows per 256 threads... 128 rows via 2 instrs
            const int col = (tid & 3) * 8;
            const int lds = (tid & ~63) * 8;     // wave-uniform elem offset
            g2l16(A + aBase + (long long)row * lda + k0 + col, &As[lds]);
            g2l16(B + bBase + (long long)row * ldb + k0 + col, &Bs[lds]);
            const int row2 = row + 64;
            const int lds2 = lds + NT * 8;
            g2l16(A + aBase + (long long)row2 * lda + k0 + col, &As[lds2]);
            g2l16(B + bBase + (long long)row2 * ldb + k0 + col, &Bs[lds2]);
        }
        __syncthreads();   // drains vmcnt(0) + barrier

        f16x8 af[4], bf[4];
        #pragma unroll
        for (int i = 0; i < 4; ++i)
            af[i] = *(const f16x8*)&As[(wm + i * 16 + l15) * BK + quad * 8];
        #pragma unroll
        for (int j = 0; j < 4; ++j)
            bf[j] = *(const f16x8*)&Bs[(wn + j * 16 + l15) * BK + quad * 8];
        #pragma unroll
        for (int i = 0; i < 4; ++i)
            #pragma unroll
            for (int j = 0; j < 4; ++j)
                acc[i][j] = __builtin_amdgcn_mfma_f32_16x16x32_f16(af[i], bf[j], acc[i][j], 0, 0, 0);
    }

    // C/D layout: col = lane&15, row = quad*4 + r (m89-verified)
    #pragma unroll
    for (int i = 0; i < 4; ++i)
        #pragma unroll
        for (int j = 0; j < 4; ++j) {
            const int row0 = wm + i * 16 + quad * 4;
            const int col  = wn + j * 16 + l15;
            float c[4];
            #pragma unroll
            for (int r = 0; r < 4; ++r) {
                c[r] = acc[i][j][r];
                if (BIAS) c[r] += biasS[col];
            }
            if constexpr (OUT_MODE == 0) {
                #pragma unroll
                for (int r = 0; r < 4; ++r)
                    Cf[(long long)b * sC + (long long)(m0 + row0 + r) * ldc + (n0 + col)] = c[r];
            } else if constexpr (OUT_MODE == 1) {
                #pragma unroll
                for (int r = 0; r < 4; ++r)
                    Ch[(long long)b * sC + (long long)(m0 + row0 + r) * ldc + (n0 + col)] = f2h(c[r]);
            } else if constexpr (OUT_MODE == 4) {
                // split-K partial: accumulate into pre-zeroed fp32 C
                #pragma unroll
                for (int r = 0; r < 4; ++r)
                    atomicAdd(&Cf[(long long)b * sC + (long long)(m0 + row0 + r) * ldc + (n0 + col)], c[r]);
            } else {  // OUT_MODE == 3: transposed fp16 [n][m], batched along m by tM
                const int mg  = m0 + row0;
                const int bb  = mg / tM;
                const int key = mg % tM;
                union { ushort_t u[4]; uint2 v; } P;
                #pragma unroll
                for (int r = 0; r < 4; ++r) P.u[r] = f2h(c[r]);
                *(uint2*)&Ch[(long long)bb * sC + (long long)(n0 + col) * ldc + key] = P.v;
            }
        }
}

// ---------- row softmax: S fp32 [8192][4096] -> P fp16 [8192][4096] (*1/32 folded) ----------
__global__ void softmax_kernel(const float* __restrict__ S, ushort_t* __restrict__ P) {
    const int row  = blockIdx.x;
    const int tid  = threadIdx.x;
    const int lane = tid & 63;
    const int wid  = tid >> 6;
    const float* s = S + (long long)row * 4096;
    float4 v[4];
    float m = -3.4e38f;
    #pragma unroll
    for (int i = 0; i < 4; ++i) {
        v[i] = ((const float4*)s)[tid + i * 256];
        m = fmaxf(fmaxf(fmaxf(m, v[i].x), fmaxf(v[i].y, v[i].z)), v[i].w);
    }
    __shared__ float redm[4], reds[4];
    #pragma unroll
    for (int o = 32; o > 0; o >>= 1) m = fmaxf(m, __shfl_down(m, o));
    if (lane == 0) redm[wid] = m;
    __syncthreads();
    m = fmaxf(fmaxf(redm[0], redm[1]), fmaxf(redm[2], redm[3]));
    float sum = 0.f;
    #pragma unroll
    for (int i = 0; i < 4; ++i) {
        v[i].x = __expf(v[i].x - m); v[i].y = __expf(v[i].y - m);
        v[i].z = __expf(v[i].z - m); v[i].w = __expf(v[i].w - m);
        sum += v[i].x + v[i].y + v[i].z + v[i].w;
    }
    #pragma unroll
    for (int o = 32; o > 0; o >>= 1) sum += __shfl_down(sum, o);
    if (lane == 0) reds[wid] = sum;
    __syncthreads();
    sum = reds[0] + reds[1] + reds[2] + reds[3];
    const float scale = 0.03125f / sum;   // 1/sqrt(1024) post-softmax scale folded in
    ushort_t* p = P + (long long)row * 4096;
    #pragma unroll
    for (int i = 0; i < 4; ++i) {
        union { ushort_t u[4]; uint2 w; } Pk;
        Pk.u[0] = f2h(v[i].x * scale); Pk.u[1] = f2h(v[i].y * scale);
        Pk.u[2] = f2h(v[i].z * scale); Pk.u[3] = f2h(v[i].w * scale);
        ((uint2*)p)[tid + i * 256] = Pk.w;
    }
}

// ---------- launch ----------
extern "C" void kernel_launch(void* const* d_in, const int* in_sizes, int n_in,
                              void* d_out, int out_size, void* d_ws, size_t ws_size,
                              hipStream_t stream) {
    const float* query = (const float*)d_in[0];
    const float* ref   = (const float*)d_in[1];
    const float* Wq    = (const float*)d_in[2];
    const float* bq    = (const float*)d_in[3];
    const float* Wk    = (const float*)d_in[4];
    const float* bk    = (const float*)d_in[5];
    const float* Wv    = (const float*)d_in[6];
    const float* bv    = (const float*)d_in[7];
    float* out = (float*)d_out;
    (void)in_sizes; (void)n_in; (void)out_size; (void)ws_size;

    char* ws = (char*)d_ws;
    // S (fp32, 134 MB) aliases Qa+Ra (dead before scores writes S)
    float*    S   = (float*)ws;
    ushort_t* Qa  = (ushort_t*)ws;                            // 8192x1024 fp16 (16 MB)
    ushort_t* Ra  = (ushort_t*)(ws + 16777216);               // 32768x1024 fp16 (64 MB)
    ushort_t* Qp  = (ushort_t*)(ws + 134217728);              // Q fp16 (16 MB)
    ushort_t* Kp  = (ushort_t*)(ws + 150994944);              // K fp16 (64 MB)
    ushort_t* Vt  = (ushort_t*)(ws + 218103808);              // V^T [b][h][key] fp16 (64 MB)
    ushort_t* WqT = (ushort_t*)(ws + 282066944);              // 2 MB each
    ushort_t* WkT = (ushort_t*)(ws + 284164096);
    ushort_t* WvT = (ushort_t*)(ws + 286261248);
    ushort_t* P   = Kp;                                       // P aliases K (dead after scores)

    // 0. zero the output (PV accumulates atomically via split-K)
    zero_kernel<<<8192, 256, 0, stream>>>((float4*)out, 2097152);

    // 1. prep: weight transpose+convert, activation convert
    wconv_kernel<<<dim3(4, 8, 3), 256, 0, stream>>>(Wq, Wk, Wv, WqT, WkT, WvT);
    aconv_kernel<<<8192, 256, 0, stream>>>(query, Qa, 2097152);
    aconv_kernel<<<32768, 256, 0, stream>>>(ref, Ra, 8388608);

    // 2. projections (fp16, bias fused)
    gemm_kernel<1, true, 1><<<dim3(8, 64, 1), NT, 0, stream>>>(
        Qa, WqT, bq, nullptr, Qp, 1024, 1024, 1024, 1024, 0, 0, 0, 0);
    gemm_kernel<1, true, 1><<<dim3(8, 256, 1), NT, 0, stream>>>(
        Ra, WkT, bk, nullptr, Kp, 1024, 1024, 1024, 1024, 0, 0, 0, 0);
    gemm_kernel<3, true, 1><<<dim3(8, 256, 1), NT, 0, stream>>>(
        Ra, WvT, bv, nullptr, Vt, 1024, 1024, 1024, 4096, 0, 0, 4194304LL, 4096);

    // 3. logits S = Q K^T (fp32 out)
    gemm_kernel<0, false, 1><<<dim3(32, 8, 8), NT, 0, stream>>>(
        Qp, Kp, nullptr, S, nullptr, 1024, 1024, 1024, 4096,
        1048576LL, 4194304LL, 4194304LL, 0);

    // 4. softmax: S fp32 -> P fp16 (compact stride 4096, *1/32 folded)
    softmax_kernel<<<8192, 256, 0, stream>>>(S, P);

    // 5. O = P V  (A = P [q][key], B = Vt [h][key] direct)
    //    split-K x4: grid z = batch*4 + k_chunk, chunk K=1024; atomicAdd into zeroed out
    gemm_kernel<4, false, 4><<<dim3(8, 8, 32), NT, 0, stream>>>(
        P, Vt, nullptr, out, nullptr, 1024, 4096, 4096, 1024,
        4194304LL, 4194304LL, 1048576LL, 0);
}

// Round 2
// 737.013 us; speedup vs baseline: 1.0694x; 1.0694x over previous
//
#include <hip/hip_runtime.h>

typedef _Float16 f16x8 __attribute__((ext_vector_type(8)));
typedef float    f32x4 __attribute__((ext_vector_type(4)));
typedef unsigned short ushort_t;

__device__ __forceinline__ ushort_t f2h(float x) {
    union { _Float16 h; ushort_t u; } c; c.h = (_Float16)x; return c.u;
}

// async global->LDS, 16 B per lane; LDS dest = wave-uniform base + lane*16
typedef __attribute__((address_space(1))) void gvoid;
typedef __attribute__((address_space(3))) void lvoid;
__device__ __forceinline__ void g2l16(const ushort_t* g, ushort_t* l) {
    __builtin_amdgcn_global_load_lds((gvoid*)g, (lvoid*)l, 16, 0, 0);
}

#define BM 128
#define BN 128
#define BK 32
#define NT 256

// ---------- weight transpose+convert: W[k][n] fp32 -> WT[n][k] fp16 ----------
__global__ void wconv_kernel(const float* __restrict__ Wq, const float* __restrict__ Wk,
                             const float* __restrict__ Wv,
                             ushort_t* __restrict__ tq, ushort_t* __restrict__ tk,
                             ushort_t* __restrict__ tv) {
    const int z = blockIdx.z;
    const float* W = (z == 0) ? Wq : (z == 1) ? Wk : Wv;
    ushort_t* T = (z == 0) ? tq : (z == 1) ? tk : tv;
    const int n  = blockIdx.x * blockDim.x + threadIdx.x;   // 0..1023
    const int kb = blockIdx.y * 128;                        // k range per block
    for (int k0 = kb; k0 < kb + 128; k0 += 8) {
        union { ushort_t u[8]; uint4 v; } H;
        #pragma unroll
        for (int e = 0; e < 8; ++e)
            H.u[e] = f2h(W[(long long)(k0 + e) * 1024 + n]);   // coalesced across lanes
        *(uint4*)&T[(long long)n * 1024 + k0] = H.v;           // per-lane contiguous 16B
    }
}

// ---------- activation convert: fp32 -> fp16 ----------
__global__ void aconv_kernel(const float* __restrict__ x, ushort_t* __restrict__ h, int n4) {
    int i = blockIdx.x * blockDim.x + threadIdx.x;
    if (i >= n4) return;
    float4 v = ((const float4*)x)[i];
    union { ushort_t u[4]; uint2 w; } H;
    H.u[0] = f2h(v.x); H.u[1] = f2h(v.y); H.u[2] = f2h(v.z); H.u[3] = f2h(v.w);
    ((uint2*)h)[i] = H.w;
}

// ---------- split-K reduce: out = p0 + p1 (fp32, vectorized) ----------
__global__ void add2_kernel(const float4* __restrict__ a, const float4* __restrict__ b,
                            float4* __restrict__ o, int n4) {
    int i = blockIdx.x * blockDim.x + threadIdx.x;
    if (i >= n4) return;
    float4 x = a[i], y = b[i];
    float4 r;
    r.x = x.x + y.x; r.y = x.y + y.y; r.z = x.z + y.z; r.w = x.w + y.w;
    o[i] = r;
}

// ---------- fp16 GEMM (m97 structure): C[M,N] = A[m][k] * B[n][k]^T (+bias) ----------
// OUT_MODE: 0 = fp32 [m][n]; 1 = fp16 [m][n]; 3 = fp16 transposed [n][m], batched along m by tM
// NSPLIT: K-split factor; blockIdx.z = batch*NSPLIT + k_chunk, each chunk covers K elems.
//         For OUT_MODE==0 with NSPLIT>1, tM carries the per-chunk output element stride.
template<int OUT_MODE, bool BIAS, int NSPLIT>
__global__ __launch_bounds__(NT, 2)
void gemm_kernel(const ushort_t* __restrict__ A, const ushort_t* __restrict__ B,
                 const float* __restrict__ bias,
                 float* __restrict__ Cf, ushort_t* __restrict__ Ch,
                 int K, int lda, int ldb, int ldc,
                 long long sA, long long sB, long long sC, int tM)
{
    __shared__ __align__(16) ushort_t As[BM * BK];
    __shared__ __align__(16) ushort_t Bs[BN * BK];
    __shared__ float biasS[BN];

    const int tid  = threadIdx.x;
    const int zz   = blockIdx.z;
    const int b    = zz / NSPLIT;           // batch index
    const int kc   = zz % NSPLIT;           // K-chunk index
    const int m0   = blockIdx.y * BM;
    const int n0   = blockIdx.x * BN;
    const int lane = tid & 63;
    const int w    = tid >> 6;
    const int wm   = (w >> 1) * 64;
    const int wn   = (w & 1) * 64;
    const int l15  = lane & 15;
    const int quad = lane >> 4;

    if (OUT_MODE == 0 && NSPLIT > 1)
        Cf += (long long)kc * (long long)tM;   // per-chunk partial buffer

    if (BIAS && tid < BN) biasS[tid] = bias[n0 + tid];

    const long long aBase = (long long)b * sA + (long long)m0 * lda;
    const long long bBase = (long long)b * sB + (long long)n0 * ldb;

    f32x4 acc[4][4];
    #pragma unroll
    for (int i = 0; i < 4; ++i)
        #pragma unroll
        for (int j = 0; j < 4; ++j)
            #pragma unroll
            for (int r = 0; r < 4; ++r) acc[i][j][r] = 0.0f;

    const int kBeg = kc * K;
    const int kEnd = kBeg + K;
    for (int k0 = kBeg; k0 < kEnd; k0 += BK) {
        __syncthreads();   // previous tile's frag reads done before overwrite
        {
            const int row = tid >> 2;            // 64 rows per 256 threads... 128 rows via 2 instrs
            const int col = (tid & 3) * 8;
            const int lds = (tid & ~63) * 8;     // wave-uniform elem offset
            g2l16(A + aBase + (long long)row * lda + k0 + col, &As[lds]);
            g2l16(B + bBase + (long long)row * ldb + k0 + col, &Bs[lds]);
            const int row2 = row + 64;
            const int lds2 = lds + NT * 8;
            g2l16(A + aBase + (long long)row2 * lda + k0 + col, &As[lds2]);
            g2l16(B + bBase + (long long)row2 * ldb + k0 + col, &Bs[lds2]);
        }
        __syncthreads();   // drains vmcnt(0) + barrier

        f16x8 af[4], bf[4];
        #pragma unroll
        for (int i = 0; i < 4; ++i)
            af[i] = *(const f16x8*)&As[(wm + i * 16 + l15) * BK + quad * 8];
        #pragma unroll
        for (int j = 0; j < 4; ++j)
            bf[j] = *(const f16x8*)&Bs[(wn + j * 16 + l15) * BK + quad * 8];
        #pragma unroll
        for (int i = 0; i < 4; ++i)
            #pragma unroll
            for (int j = 0; j < 4; ++j)
                acc[i][j] = __builtin_amdgcn_mfma_f32_16x16x32_f16(af[i], bf[j], acc[i][j], 0, 0, 0);
    }

    // C/D layout: col = lane&15, row = quad*4 + r (m89-verified)
    #pragma unroll
    for (int i = 0; i < 4; ++i)
        #pragma unroll
        for (int j = 0; j < 4; ++j) {
            const int row0 = wm + i * 16 + quad * 4;
            const int col  = wn + j * 16 + l15;
            float c[4];
            #pragma unroll
            for (int r = 0; r < 4; ++r) {
                c[r] = acc[i][j][r];
                if (BIAS) c[r] += biasS[col];
            }
            if constexpr (OUT_MODE == 0) {
                #pragma unroll
                for (int r = 0; r < 4; ++r)
                    Cf[(long long)b * sC + (long long)(m0 + row0 + r) * ldc + (n0 + col)] = c[r];
            } else if constexpr (OUT_MODE == 1) {
                #pragma unroll
                for (int r = 0; r < 4; ++r)
                    Ch[(long long)b * sC + (long long)(m0 + row0 + r) * ldc + (n0 + col)] = f2h(c[r]);
            } else {  // OUT_MODE == 3: transposed fp16 [n][m], batched along m by tM
                const int mg  = m0 + row0;
                const int bb  = mg / tM;
                const int key = mg % tM;
                union { ushort_t u[4]; uint2 v; } P;
                #pragma unroll
                for (int r = 0; r < 4; ++r) P.u[r] = f2h(c[r]);
                *(uint2*)&Ch[(long long)bb * sC + (long long)(n0 + col) * ldc + key] = P.v;
            }
        }
}

// ---------- row softmax: S fp32 [8192][4096] -> P fp16 [8192][4096] (*1/32 folded) ----------
__global__ void softmax_kernel(const float* __restrict__ S, ushort_t* __restrict__ P) {
    const int row  = blockIdx.x;
    const int tid  = threadIdx.x;
    const int lane = tid & 63;
    const int wid  = tid >> 6;
    const float* s = S + (long long)row * 4096;
    float4 v[4];
    float m = -3.4e38f;
    #pragma unroll
    for (int i = 0; i < 4; ++i) {
        v[i] = ((const float4*)s)[tid + i * 256];
        m = fmaxf(fmaxf(fmaxf(m, v[i].x), fmaxf(v[i].y, v[i].z)), v[i].w);
    }
    __shared__ float redm[4], reds[4];
    #pragma unroll
    for (int o = 32; o > 0; o >>= 1) m = fmaxf(m, __shfl_down(m, o));
    if (lane == 0) redm[wid] = m;
    __syncthreads();
    m = fmaxf(fmaxf(redm[0], redm[1]), fmaxf(redm[2], redm[3]));
    float sum = 0.f;
    #pragma unroll
    for (int i = 0; i < 4; ++i) {
        v[i].x = __expf(v[i].x - m); v[i].y = __expf(v[i].y - m);
        v[i].z = __expf(v[i].z - m); v[i].w = __expf(v[i].w - m);
        sum += v[i].x + v[i].y + v[i].z + v[i].w;
    }
    #pragma unroll
    for (int o = 32; o > 0; o >>= 1) sum += __shfl_down(sum, o);
    if (lane == 0) reds[wid] = sum;
    __syncthreads();
    sum = reds[0] + reds[1] + reds[2] + reds[3];
    const float scale = 0.03125f / sum;   // 1/sqrt(1024) post-softmax scale folded in
    ushort_t* p = P + (long long)row * 4096;
    #pragma unroll
    for (int i = 0; i < 4; ++i) {
        union { ushort_t u[4]; uint2 w; } Pk;
        Pk.u[0] = f2h(v[i].x * scale); Pk.u[1] = f2h(v[i].y * scale);
        Pk.u[2] = f2h(v[i].z * scale); Pk.u[3] = f2h(v[i].w * scale);
        ((uint2*)p)[tid + i * 256] = Pk.w;
    }
}

// ---------- launch ----------
extern "C" void kernel_launch(void* const* d_in, const int* in_sizes, int n_in,
                              void* d_out, int out_size, void* d_ws, size_t ws_size,
                              hipStream_t stream) {
    const float* query = (const float*)d_in[0];
    const float* ref   = (const float*)d_in[1];
    const float* Wq    = (const float*)d_in[2];
    const float* bq    = (const float*)d_in[3];
    const float* Wk    = (const float*)d_in[4];
    const float* bk    = (const float*)d_in[5];
    const float* Wv    = (const float*)d_in[6];
    const float* bv    = (const float*)d_in[7];
    float* out = (float*)d_out;
    (void)in_sizes; (void)n_in; (void)out_size; (void)ws_size;

    char* ws = (char*)d_ws;
    // S (fp32, 134 MB) aliases Qa+Ra (dead before scores writes S)
    // After softmax, S region is dead -> reused for PV split-K partials (2 x 32 MB)
    float*    S   = (float*)ws;
    ushort_t* Qa  = (ushort_t*)ws;                            // 8192x1024 fp16 (16 MB)
    ushort_t* Ra  = (ushort_t*)(ws + 16777216);               // 32768x1024 fp16 (64 MB)
    ushort_t* Qp  = (ushort_t*)(ws + 134217728);              // Q fp16 (16 MB)
    ushort_t* Kp  = (ushort_t*)(ws + 150994944);              // K fp16 (64 MB)
    ushort_t* Vt  = (ushort_t*)(ws + 218103808);              // V^T [b][h][key] fp16 (64 MB)
    ushort_t* WqT = (ushort_t*)(ws + 282066944);              // 2 MB each
    ushort_t* WkT = (ushort_t*)(ws + 284164096);
    ushort_t* WvT = (ushort_t*)(ws + 286261248);
    ushort_t* P   = Kp;                                       // P aliases K (dead after scores)
    float*    Ppart = (float*)ws;                             // PV partials: 2 x 8388608 floats

    // 1. prep: weight transpose+convert, activation convert
    wconv_kernel<<<dim3(4, 8, 3), 256, 0, stream>>>(Wq, Wk, Wv, WqT, WkT, WvT);
    aconv_kernel<<<8192, 256, 0, stream>>>(query, Qa, 2097152);
    aconv_kernel<<<32768, 256, 0, stream>>>(ref, Ra, 8388608);

    // 2. projections (fp16, bias fused)
    gemm_kernel<1, true, 1><<<dim3(8, 64, 1), NT, 0, stream>>>(
        Qa, WqT, bq, nullptr, Qp, 1024, 1024, 1024, 1024, 0, 0, 0, 0);
    gemm_kernel<1, true, 1><<<dim3(8, 256, 1), NT, 0, stream>>>(
        Ra, WkT, bk, nullptr, Kp, 1024, 1024, 1024, 1024, 0, 0, 0, 0);
    gemm_kernel<3, true, 1><<<dim3(8, 256, 1), NT, 0, stream>>>(
        Ra, WvT, bv, nullptr, Vt, 1024, 1024, 1024, 4096, 0, 0, 4194304LL, 4096);

    // 3. logits S = Q K^T (fp32 out)
    gemm_kernel<0, false, 1><<<dim3(32, 8, 8), NT, 0, stream>>>(
        Qp, Kp, nullptr, S, nullptr, 1024, 1024, 1024, 4096,
        1048576LL, 4194304LL, 4194304LL, 0);

    // 4. softmax: S fp32 -> P fp16 (compact stride 4096, *1/32 folded)
    softmax_kernel<<<8192, 256, 0, stream>>>(S, P);

    // 5. O = P V  (A = P [q][key], B = Vt [h][key] direct)
    //    split-K x2 into fp32 partial buffers (S region, dead), then add.
    //    grid z = batch*2 + k_chunk, chunk K=2048; tM = per-chunk elem stride (8M floats)
    gemm_kernel<0, false, 2><<<dim3(8, 8, 16), NT, 0, stream>>>(
        P, Vt, nullptr, Ppart, nullptr, 2048, 4096, 4096, 1024,
        4194304LL, 4194304LL, 1048576LL, 8388608);

    // 6. out = part0 + part1
    add2_kernel<<<8192, 256, 0, stream>>>(
        (const float4*)Ppart, (const float4*)(Ppart + 8388608), (float4*)out, 2097152);
}

// Round 3
// 640.005 us; speedup vs baseline: 1.2315x; 1.1516x over previous
//
#include <hip/hip_runtime.h>

typedef _Float16 f16x8 __attribute__((ext_vector_type(8)));
typedef float    f32x4 __attribute__((ext_vector_type(4)));
typedef unsigned short ushort_t;

__device__ __forceinline__ ushort_t f2h(float x) {
    union { _Float16 h; ushort_t u; } c; c.h = (_Float16)x; return c.u;
}

// async global->LDS, 16 B per lane; LDS dest = wave-uniform base + lane*16
typedef __attribute__((address_space(1))) void gvoid;
typedef __attribute__((address_space(3))) void lvoid;
__device__ __forceinline__ void g2l16(const ushort_t* g, ushort_t* l) {
    __builtin_amdgcn_global_load_lds((gvoid*)g, (lvoid*)l, 16, 0, 0);
}

#define BM 128
#define BN 128
#define BK 32
#define NT 256

// ---------- weight transpose+convert: W[k][n] fp32 -> WT[n][k] fp16 ----------
__global__ void wconv_kernel(const float* __restrict__ Wq, const float* __restrict__ Wk,
                             const float* __restrict__ Wv,
                             ushort_t* __restrict__ tq, ushort_t* __restrict__ tk,
                             ushort_t* __restrict__ tv) {
    const int z = blockIdx.z;
    const float* W = (z == 0) ? Wq : (z == 1) ? Wk : Wv;
    ushort_t* T = (z == 0) ? tq : (z == 1) ? tk : tv;
    const int n  = blockIdx.x * blockDim.x + threadIdx.x;   // 0..1023
    const int kb = blockIdx.y * 128;                        // k range per block
    for (int k0 = kb; k0 < kb + 128; k0 += 8) {
        union { ushort_t u[8]; uint4 v; } H;
        #pragma unroll
        for (int e = 0; e < 8; ++e)
            H.u[e] = f2h(W[(long long)(k0 + e) * 1024 + n]);   // coalesced across lanes
        *(uint4*)&T[(long long)n * 1024 + k0] = H.v;           // per-lane contiguous 16B
    }
}

// ---------- activation convert: fp32 -> fp16 ----------
__global__ void aconv_kernel(const float* __restrict__ x, ushort_t* __restrict__ h, int n4) {
    int i = blockIdx.x * blockDim.x + threadIdx.x;
    if (i >= n4) return;
    float4 v = ((const float4*)x)[i];
    union { ushort_t u[4]; uint2 w; } H;
    H.u[0] = f2h(v.x); H.u[1] = f2h(v.y); H.u[2] = f2h(v.z); H.u[3] = f2h(v.w);
    ((uint2*)h)[i] = H.w;
}

// ---------- split-K reduce: out = p0 + p1 (fp32, vectorized) ----------
__global__ void add2_kernel(const float4* __restrict__ a, const float4* __restrict__ b,
                            float4* __restrict__ o, int n4) {
    int i = blockIdx.x * blockDim.x + threadIdx.x;
    if (i >= n4) return;
    float4 x = a[i], y = b[i];
    float4 r;
    r.x = x.x + y.x; r.y = x.y + y.y; r.z = x.z + y.z; r.w = x.w + y.w;
    o[i] = r;
}

// ---------- 128x128 fp16 GEMM (m97 structure) — kept for the small Q projection ----------
template<int OUT_MODE, bool BIAS, int NSPLIT>
__global__ __launch_bounds__(NT, 2)
void gemm_kernel(const ushort_t* __restrict__ A, const ushort_t* __restrict__ B,
                 const float* __restrict__ bias,
                 float* __restrict__ Cf, ushort_t* __restrict__ Ch,
                 int K, int lda, int ldb, int ldc,
                 long long sA, long long sB, long long sC, int tM)
{
    __shared__ __align__(16) ushort_t As[BM * BK];
    __shared__ __align__(16) ushort_t Bs[BN * BK];
    __shared__ float biasS[BN];

    const int tid  = threadIdx.x;
    const int zz   = blockIdx.z;
    const int b    = zz / NSPLIT;
    const int kc   = zz % NSPLIT;
    const int m0   = blockIdx.y * BM;
    const int n0   = blockIdx.x * BN;
    const int lane = tid & 63;
    const int w    = tid >> 6;
    const int wm   = (w >> 1) * 64;
    const int wn   = (w & 1) * 64;
    const int l15  = lane & 15;
    const int quad = lane >> 4;

    if (OUT_MODE == 0 && NSPLIT > 1)
        Cf += (long long)kc * (long long)tM;

    if (BIAS && tid < BN) biasS[tid] = bias[n0 + tid];

    const long long aBase = (long long)b * sA + (long long)m0 * lda;
    const long long bBase = (long long)b * sB + (long long)n0 * ldb;

    f32x4 acc[4][4];
    #pragma unroll
    for (int i = 0; i < 4; ++i)
        #pragma unroll
        for (int j = 0; j < 4; ++j)
            #pragma unroll
            for (int r = 0; r < 4; ++r) acc[i][j][r] = 0.0f;

    const int kBeg = kc * K;
    const int kEnd = kBeg + K;
    for (int k0 = kBeg; k0 < kEnd; k0 += BK) {
        __syncthreads();
        {
            const int row = tid >> 2;
            const int col = (tid & 3) * 8;
            const int lds = (tid & ~63) * 8;
            g2l16(A + aBase + (long long)row * lda + k0 + col, &As[lds]);
            g2l16(B + bBase + (long long)row * ldb + k0 + col, &Bs[lds]);
            const int row2 = row + 64;
            const int lds2 = lds + NT * 8;
            g2l16(A + aBase + (long long)row2 * lda + k0 + col, &As[lds2]);
            g2l16(B + bBase + (long long)row2 * ldb + k0 + col, &Bs[lds2]);
        }
        __syncthreads();

        f16x8 af[4], bf[4];
        #pragma unroll
        for (int i = 0; i < 4; ++i)
            af[i] = *(const f16x8*)&As[(wm + i * 16 + l15) * BK + quad * 8];
        #pragma unroll
        for (int j = 0; j < 4; ++j)
            bf[j] = *(const f16x8*)&Bs[(wn + j * 16 + l15) * BK + quad * 8];
        #pragma unroll
        for (int i = 0; i < 4; ++i)
            #pragma unroll
            for (int j = 0; j < 4; ++j)
                acc[i][j] = __builtin_amdgcn_mfma_f32_16x16x32_f16(af[i], bf[j], acc[i][j], 0, 0, 0);
    }

    #pragma unroll
    for (int i = 0; i < 4; ++i)
        #pragma unroll
        for (int j = 0; j < 4; ++j) {
            const int row0 = wm + i * 16 + quad * 4;
            const int col  = wn + j * 16 + l15;
            float c[4];
            #pragma unroll
            for (int r = 0; r < 4; ++r) {
                c[r] = acc[i][j][r];
                if (BIAS) c[r] += biasS[col];
            }
            if constexpr (OUT_MODE == 0) {
                #pragma unroll
                for (int r = 0; r < 4; ++r)
                    Cf[(long long)b * sC + (long long)(m0 + row0 + r) * ldc + (n0 + col)] = c[r];
            } else if constexpr (OUT_MODE == 1) {
                #pragma unroll
                for (int r = 0; r < 4; ++r)
                    Ch[(long long)b * sC + (long long)(m0 + row0 + r) * ldc + (n0 + col)] = f2h(c[r]);
            } else {
                const int mg  = m0 + row0;
                const int bb  = mg / tM;
                const int key = mg % tM;
                union { ushort_t u[4]; uint2 v; } P;
                #pragma unroll
                for (int r = 0; r < 4; ++r) P.u[r] = f2h(c[r]);
                *(uint2*)&Ch[(long long)bb * sC + (long long)(n0 + col) * ldc + key] = P.v;
            }
        }
}

// ---------- 256x256 8-phase fp16 GEMM (T2+T3+T4+T5): C[M,N] = A[m][k]*B[n][k]^T ----------
// 512 threads = 8 waves (2M x 4N), per-wave 128x64 out, BK=64, LDS 128 KiB double-buffered.
// Counted vmcnt: per-tile stage slots {q0: A-hi(t+1), q1: B-lo(t+2), q2: B-hi(t+2), q3: A-lo(t+2)},
// waits vmcnt(10)@q1 / vmcnt(8)@q3 drain exactly through the chunk needed next (hand-verified FIFO).
// LDS XOR-swizzle byte^=(row&7)<<4, applied on ds_read and pre-applied on the global stage source.
__device__ __forceinline__ f16x8 ldfrag(const ushort_t* base, int row, int ks, int quad) {
    int byte_ = (row << 7) + (ks << 6) + (quad << 4);
    byte_ ^= (row & 7) << 4;
    return *(const f16x8*)((const char*)base + byte_);
}

template<int OUT_MODE, bool BIAS, int NSPLIT>
__global__ __launch_bounds__(512, 2)
void gemm256_kernel(const ushort_t* __restrict__ A, const ushort_t* __restrict__ B,
                    const float* __restrict__ bias,
                    float* __restrict__ Cf, ushort_t* __restrict__ Ch,
                    int K, int lda, int ldb, int ldc,
                    long long sA, long long sB, long long sC, int tM)
{
    __shared__ __align__(16) ushort_t As[2][256 * 64];
    __shared__ __align__(16) ushort_t Bs[2][256 * 64];

    const int tid  = threadIdx.x;
    const int lane = tid & 63;
    const int wid  = tid >> 6;
    const int wr   = wid >> 2;        // 0..1
    const int wc   = wid & 3;         // 0..3
    const int quad = lane >> 4;
    const int l15  = lane & 15;

    const int zz = blockIdx.z;
    const int b  = zz / NSPLIT;
    const int kc = zz % NSPLIT;
    const int m0 = blockIdx.y * 256;
    const int n0 = blockIdx.x * 256;

    const ushort_t* Ab = A + (long long)b * sA + (long long)m0 * lda;
    const ushort_t* Bb = B + (long long)b * sB + (long long)n0 * ldb;

    float* Cfp = Cf;
    if (OUT_MODE == 0 && NSPLIT > 1) Cfp = Cf + (long long)kc * (long long)tM;

    const int NTILES = K >> 6;        // >= 2 for all our shapes
    const int kBeg   = kc * K;
    const int tlast  = NTILES - 1;

    // per-lane pre-swizzled stage source (64-row chunk per instruction; 1 KiB/wave)
    const int srow = (wid << 3) + (lane >> 3);                    // 0..63
    const int scol = ((lane & 7) ^ ((lane >> 3) & 7)) << 3;       // elem col, swizzle pre-applied

#define STAGE_A(bf, r0, kcol) g2l16(Ab + (long long)((r0) + srow) * lda + (kcol) + scol, \
                                    &As[bf][((r0) + (wid << 3)) << 6])
#define STAGE_B(bf, r0, kcol) g2l16(Bb + (long long)((r0) + srow) * ldb + (kcol) + scol, \
                                    &Bs[bf][((r0) + (wid << 3)) << 6])
#define BAR()  __builtin_amdgcn_s_barrier()
#define SB0()  __builtin_amdgcn_sched_barrier(0)
#define VMCNT(n) asm volatile("s_waitcnt vmcnt(" #n ")" ::: "memory")

    f32x4 acc[8][4];
    #pragma unroll
    for (int i = 0; i < 8; ++i)
        #pragma unroll
        for (int j = 0; j < 4; ++j)
            #pragma unroll
            for (int r = 0; r < 4; ++r) acc[i][j][r] = 0.0f;

    // ---- prologue: tile0 complete (8 instr), tile1 B + A-lo chunks (6 instr) ----
    {
        const int k0 = kBeg, k1 = kBeg + 64;
        STAGE_B(0, 0,   k0); STAGE_B(0, 64,  k0);    // B-lo(0)
        STAGE_B(0, 128, k0); STAGE_B(0, 192, k0);    // B-hi(0)
        STAGE_A(0, 0,   k0); STAGE_A(0, 128, k0);    // A-lo chunks(0)  (rows 0-63,128-191)
        STAGE_A(0, 64,  k0); STAGE_A(0, 192, k0);    // A-hi chunks(0)  (rows 64-127,192-255)
        STAGE_B(1, 0,   k1); STAGE_B(1, 64,  k1);
        STAGE_B(1, 128, k1); STAGE_B(1, 192, k1);
        STAGE_A(1, 0,   k1); STAGE_A(1, 128, k1);
        VMCNT(8);            // 14 in flight -> drain 6: B(0) + A-lo(0), exactly phase-0's needs
        BAR(); SB0();
    }

    const int arow = wr * 128 + l15;
    const int brow = wc * 64 + l15;
    f16x8 bfr[4][2], afr[2][2];

#define PHASE_AFR(bf, q) \
    afr[0][0] = ldfrag(&As[bf][0], arow + (q)*32,      0, quad); \
    afr[0][1] = ldfrag(&As[bf][0], arow + (q)*32,      1, quad); \
    afr[1][0] = ldfrag(&As[bf][0], arow + (q)*32 + 16, 0, quad); \
    afr[1][1] = ldfrag(&As[bf][0], arow + (q)*32 + 16, 1, quad);

#define PHASE_MFMA(q) \
    _Pragma("unroll") \
    for (int m2 = 0; m2 < 2; ++m2) \
        _Pragma("unroll") \
        for (int j = 0; j < 4; ++j) { \
            acc[(q)*2+m2][j] = __builtin_amdgcn_mfma_f32_16x16x32_f16(afr[m2][0], bfr[j][0], acc[(q)*2+m2][j], 0, 0, 0); \
            acc[(q)*2+m2][j] = __builtin_amdgcn_mfma_f32_16x16x32_f16(afr[m2][1], bfr[j][1], acc[(q)*2+m2][j], 0, 0, 0); \
        }

#define TILE_BODY(bf, kn1, kn2) { \
    /* phase 0: B frags (8 reads) + A quad0 (4 reads); stage A-hi(t+1) */ \
    _Pragma("unroll") \
    for (int j = 0; j < 4; ++j) { \
        bfr[j][0] = ldfrag(&Bs[bf][0], brow + j*16, 0, quad); \
        bfr[j][1] = ldfrag(&Bs[bf][0], brow + j*16, 1, quad); \
    } \
    PHASE_AFR(bf, 0); \
    STAGE_A((bf) ^ 1, 64, kn1); STAGE_A((bf) ^ 1, 192, kn1); \
    BAR(); __builtin_amdgcn_s_setprio(1); \
    PHASE_MFMA(0); \
    __builtin_amdgcn_s_setprio(0); BAR(); SB0(); \
    /* phase 1: A quad1; stage B-lo(t+2) */ \
    PHASE_AFR(bf, 1); \
    STAGE_B(bf, 0, kn2); STAGE_B(bf, 64, kn2); \
    BAR(); __builtin_amdgcn_s_setprio(1); \
    PHASE_MFMA(1); \
    __builtin_amdgcn_s_setprio(0); VMCNT(10); BAR(); SB0(); \
    /* phase 2: A quad2; stage B-hi(t+2) */ \
    PHASE_AFR(bf, 2); \
    STAGE_B(bf, 128, kn2); STAGE_B(bf, 192, kn2); \
    BAR(); __builtin_amdgcn_s_setprio(1); \
    PHASE_MFMA(2); \
    __builtin_amdgcn_s_setprio(0); BAR(); SB0(); \
    /* phase 3: A quad3; stage A-lo(t+2) */ \
    PHASE_AFR(bf, 3); \
    STAGE_A(bf, 0, kn2); STAGE_A(bf, 128, kn2); \
    BAR(); __builtin_amdgcn_s_setprio(1); \
    PHASE_MFMA(3); \
    __builtin_amdgcn_s_setprio(0); VMCNT(8); BAR(); SB0(); \
}

    for (int t = 0; t < NTILES; t += 2) {
        {
            const int kn1 = kBeg + (((t + 1) < NTILES ? (t + 1) : tlast) << 6);
            const int kn2 = kBeg + (((t + 2) < NTILES ? (t + 2) : tlast) << 6);
            TILE_BODY(0, kn1, kn2);
        }
        {
            const int kn1 = kBeg + (((t + 2) < NTILES ? (t + 2) : tlast) << 6);
            const int kn2 = kBeg + (((t + 3) < NTILES ? (t + 3) : tlast) << 6);
            TILE_BODY(1, kn1, kn2);
        }
    }

    VMCNT(0);   // drain tail prefetches before reusing anything

    float biasv[4];
    if (BIAS) {
        #pragma unroll
        for (int j = 0; j < 4; ++j)
            biasv[j] = bias[n0 + wc * 64 + j * 16 + l15];
    }

    // C/D layout: col = lane&15, row = quad*4 + r (m89-verified)
    #pragma unroll
    for (int mi = 0; mi < 8; ++mi) {
        const int row0 = wr * 128 + mi * 16 + quad * 4;
        #pragma unroll
        for (int j = 0; j < 4; ++j) {
            const int col = wc * 64 + j * 16 + l15;
            float c[4];
            #pragma unroll
            for (int r = 0; r < 4; ++r) {
                c[r] = acc[mi][j][r];
                if (BIAS) c[r] += biasv[j];
            }
            if constexpr (OUT_MODE == 0) {
                #pragma unroll
                for (int r = 0; r < 4; ++r)
                    Cfp[(long long)b * sC + (long long)(m0 + row0 + r) * ldc + (n0 + col)] = c[r];
            } else if constexpr (OUT_MODE == 1) {
                #pragma unroll
                for (int r = 0; r < 4; ++r)
                    Ch[(long long)b * sC + (long long)(m0 + row0 + r) * ldc + (n0 + col)] = f2h(c[r]);
            } else {  // OUT_MODE == 3: transposed fp16 [n][m], batched along m by tM
                const int mg  = m0 + row0;
                const int bb2 = mg / tM;
                const int key = mg % tM;
                union { ushort_t u[4]; uint2 v; } Pp;
                #pragma unroll
                for (int r = 0; r < 4; ++r) Pp.u[r] = f2h(c[r]);
                *(uint2*)&Ch[(long long)bb2 * sC + (long long)(n0 + col) * ldc + key] = Pp.v;
            }
        }
    }
#undef STAGE_A
#undef STAGE_B
#undef BAR
#undef SB0
#undef VMCNT
#undef PHASE_AFR
#undef PHASE_MFMA
#undef TILE_BODY
}

// ---------- row softmax: S fp32 [8192][4096] -> P fp16 [8192][4096] (*1/32 folded) ----------
__global__ void softmax_kernel(const float* __restrict__ S, ushort_t* __restrict__ P) {
    const int row  = blockIdx.x;
    const int tid  = threadIdx.x;
    const int lane = tid & 63;
    const int wid  = tid >> 6;
    const float* s = S + (long long)row * 4096;
    float4 v[4];
    float m = -3.4e38f;
    #pragma unroll
    for (int i = 0; i < 4; ++i) {
        v[i] = ((const float4*)s)[tid + i * 256];
        m = fmaxf(fmaxf(fmaxf(m, v[i].x), fmaxf(v[i].y, v[i].z)), v[i].w);
    }
    __shared__ float redm[4], reds[4];
    #pragma unroll
    for (int o = 32; o > 0; o >>= 1) m = fmaxf(m, __shfl_down(m, o));
    if (lane == 0) redm[wid] = m;
    __syncthreads();
    m = fmaxf(fmaxf(redm[0], redm[1]), fmaxf(redm[2], redm[3]));
    float sum = 0.f;
    #pragma unroll
    for (int i = 0; i < 4; ++i) {
        v[i].x = __expf(v[i].x - m); v[i].y = __expf(v[i].y - m);
        v[i].z = __expf(v[i].z - m); v[i].w = __expf(v[i].w - m);
        sum += v[i].x + v[i].y + v[i].z + v[i].w;
    }
    #pragma unroll
    for (int o = 32; o > 0; o >>= 1) sum += __shfl_down(sum, o);
    if (lane == 0) reds[wid] = sum;
    __syncthreads();
    sum = reds[0] + reds[1] + reds[2] + reds[3];
    const float scale = 0.03125f / sum;   // 1/sqrt(1024) post-softmax scale folded in
    ushort_t* p = P + (long long)row * 4096;
    #pragma unroll
    for (int i = 0; i < 4; ++i) {
        union { ushort_t u[4]; uint2 w; } Pk;
        Pk.u[0] = f2h(v[i].x * scale); Pk.u[1] = f2h(v[i].y * scale);
        Pk.u[2] = f2h(v[i].z * scale); Pk.u[3] = f2h(v[i].w * scale);
        ((uint2*)p)[tid + i * 256] = Pk.w;
    }
}

// ---------- launch ----------
extern "C" void kernel_launch(void* const* d_in, const int* in_sizes, int n_in,
                              void* d_out, int out_size, void* d_ws, size_t ws_size,
                              hipStream_t stream) {
    const float* query = (const float*)d_in[0];
    const float* ref   = (const float*)d_in[1];
    const float* Wq    = (const float*)d_in[2];
    const float* bq    = (const float*)d_in[3];
    const float* Wk    = (const float*)d_in[4];
    const float* bk    = (const float*)d_in[5];
    const float* Wv    = (const float*)d_in[6];
    const float* bv    = (const float*)d_in[7];
    float* out = (float*)d_out;
    (void)in_sizes; (void)n_in; (void)out_size; (void)ws_size;

    char* ws = (char*)d_ws;
    // S (fp32, 134 MB) aliases Qa+Ra (dead before scores writes S)
    // After softmax, S region is dead -> reused for PV split-K partials (2 x 32 MB)
    float*    S   = (float*)ws;
    ushort_t* Qa  = (ushort_t*)ws;                            // 8192x1024 fp16 (16 MB)
    ushort_t* Ra  = (ushort_t*)(ws + 16777216);               // 32768x1024 fp16 (64 MB)
    ushort_t* Qp  = (ushort_t*)(ws + 134217728);              // Q fp16 (16 MB)
    ushort_t* Kp  = (ushort_t*)(ws + 150994944);              // K fp16 (64 MB)
    ushort_t* Vt  = (ushort_t*)(ws + 218103808);              // V^T [b][h][key] fp16 (64 MB)
    ushort_t* WqT = (ushort_t*)(ws + 282066944);              // 2 MB each
    ushort_t* WkT = (ushort_t*)(ws + 284164096);
    ushort_t* WvT = (ushort_t*)(ws + 286261248);
    ushort_t* P   = Kp;                                       // P aliases K (dead after scores)
    float*    Ppart = (float*)ws;                             // PV partials: 2 x 8388608 floats

    // 1. prep: weight transpose+convert, activation convert
    wconv_kernel<<<dim3(4, 8, 3), 256, 0, stream>>>(Wq, Wk, Wv, WqT, WkT, WvT);
    aconv_kernel<<<8192, 256, 0, stream>>>(query, Qa, 2097152);
    aconv_kernel<<<32768, 256, 0, stream>>>(ref, Ra, 8388608);

    // 2. projections (fp16, bias fused). Q stays on 128^2 (grid would be 0.5/CU at 256^2).
    gemm_kernel<1, true, 1><<<dim3(8, 64, 1), NT, 0, stream>>>(
        Qa, WqT, bq, nullptr, Qp, 1024, 1024, 1024, 1024, 0, 0, 0, 0);
    gemm256_kernel<1, true, 1><<<dim3(4, 128, 1), 512, 0, stream>>>(
        Ra, WkT, bk, nullptr, Kp, 1024, 1024, 1024, 1024, 0, 0, 0, 0);
    gemm256_kernel<3, true, 1><<<dim3(4, 128, 1), 512, 0, stream>>>(
        Ra, WvT, bv, nullptr, Vt, 1024, 1024, 1024, 4096, 0, 0, 4194304LL, 4096);

    // 3. logits S = Q K^T (fp32 out)
    gemm256_kernel<0, false, 1><<<dim3(16, 4, 8), 512, 0, stream>>>(
        Qp, Kp, nullptr, S, nullptr, 1024, 1024, 1024, 4096,
        1048576LL, 4194304LL, 4194304LL, 0);

    // 4. softmax: S fp32 -> P fp16 (compact stride 4096, *1/32 folded)
    softmax_kernel<<<8192, 256, 0, stream>>>(S, P);

    // 5. O = P V  (A = P [q][key], B = Vt [h][key] direct)
    //    split-K x2 into fp32 partial buffers (S region, dead), then add.
    //    grid 4x4x16 = 256 blocks = 1 block/CU (8-phase design point)
    gemm256_kernel<0, false, 2><<<dim3(4, 4, 16), 512, 0, stream>>>(
        P, Vt, nullptr, Ppart, nullptr, 2048, 4096, 4096, 1024,
        4194304LL, 4194304LL, 1048576LL, 8388608);

    // 6. out = part0 + part1
    add2_kernel<<<8192, 256, 0, stream>>>(
        (const float4*)Ppart, (const float4*)(Ppart + 8388608), (float4*)out, 2097152);
}